// Round 3
// baseline (326.060 us; speedup 1.0000x reference)
//
#include <hip/hip_runtime.h>
#include <hip/hip_bf16.h>

// Problem constants (fixed by reference)
#define N_ROWS 200000
#define DIMS   128
#define E_UPD  100000
#define TILE   64
#define NTILES (N_ROWS / TILE)   // 3125, exact
#define FSTRIDE 264              // 256 + 8 pad (keeps 16B align: 528B = 16*33)
#define HSTRIDE 136              // 128 + 8 pad (272B = 16*17)
#define MAIN_GRID 768            // 3 blocks/CU * 256 CUs; work-stealing balances

typedef float f32x4 __attribute__((ext_vector_type(4)));
typedef __bf16 bf16x8 __attribute__((ext_vector_type(8)));
typedef unsigned short u16x8 __attribute__((ext_vector_type(8)));

static __device__ __forceinline__ unsigned short f2b(float f) {
    __hip_bfloat16 b = __float2bfloat16(f);
    return __builtin_bit_cast(unsigned short, b);
}

__global__ void fill_inv(int* inv, int* counter) {
    int i = blockIdx.x * blockDim.x + threadIdx.x;
    if (i < N_ROWS) inv[i] = -1;
    if (i == 0) counter[0] = 0;
}

__global__ void scatter_inv(const int* __restrict__ src, int* __restrict__ inv) {
    int e = blockIdx.x * blockDim.x + threadIdx.x;
    if (e < E_UPD) inv[src[e]] = e;
}

__launch_bounds__(512)
__global__ void ctdg_main(
    const float* __restrict__ memory,      // [N][129]
    const float* __restrict__ last_update, // [N]
    const float* __restrict__ umsg,        // [E][129]
    const float* __restrict__ uts,         // [E]
    const float* __restrict__ semb,        // [N][128]
    const float* __restrict__ W1,          // [256][128]
    const float* __restrict__ b1,          // [128]
    const float* __restrict__ W2,          // [128][128]
    const float* __restrict__ b2,          // [128]
    const float* __restrict__ e_lamb_p,    // [1]
    const float* __restrict__ now_p,       // [1]
    const int*   __restrict__ inv,         // [N] (ws)
    int*         __restrict__ counter,     // work-steal counter (ws)
    float*       __restrict__ out)         // [N][128] fp32  (ref output dtype)
{
    __shared__ __align__(16) unsigned short feat[TILE][FSTRIDE];
    __shared__ __align__(16) unsigned short h1s[TILE][HSTRIDE];
    __shared__ float rdecay[TILE];
    __shared__ float rcinv[TILE];
    __shared__ float rscale[TILE];
    __shared__ int   ridx[TILE];
    __shared__ int   s_tile;

    const int tid  = threadIdx.x;
    const int lane = tid & 63;
    const int wave = tid >> 6;     // 0..7 — owns output cols [wave*16, wave*16+16)
    const int quad = lane >> 4;    // 0..3
    const int l16  = lane & 15;
    const int wn   = wave * 16;

    // ---- persistent B-fragments: B[k = t*32 + quad*8 + j][n = wn + l16] ----
    u16x8 w1f[8];
    u16x8 w2f[4];
    #pragma unroll
    for (int t = 0; t < 8; ++t) {
        #pragma unroll
        for (int j = 0; j < 8; ++j)
            w1f[t][j] = f2b(W1[(t*32 + quad*8 + j)*128 + wn + l16]);
    }
    #pragma unroll
    for (int t = 0; t < 4; ++t) {
        #pragma unroll
        for (int j = 0; j < 8; ++j)
            w2f[t][j] = f2b(W2[(t*32 + quad*8 + j)*128 + wn + l16]);
    }
    const float b1v   = b1[wn + l16];
    const float b2v   = b2[wn + l16];
    const float el    = e_lamb_p[0];
    const float nowt  = now_p[0];
    const float inv30 = 1.0f / 30.0f;   // 1/LAMB == 1/OUTPUT

    for (;;) {
        if (tid == 0) s_tile = atomicAdd(counter, 1);
        __syncthreads();
        const int tile = s_tile;
        if (tile >= NTILES) break;
        const int row0 = tile * TILE;

        // ---- stage 1: per-row scalars (one thread per row) ----
        if (tid < TILE) {
            const int g = row0 + tid;
            const float lu = last_update[g];
            const int e = inv[g];
            float dec = 1.0f, cnt, lun;
            const float mc = memory[(size_t)g*129 + 128];
            if (e >= 0) {
                const float ts = uts[e];
                dec = __expf((lu - ts) * inv30);
                cnt = fmaf(mc, dec, umsg[(size_t)e*129 + 128]);
                lun = ts;
            } else {
                cnt = mc;
                lun = lu;
            }
            rdecay[tid] = dec;
            rcinv[tid]  = 1.0f / (cnt + 1e-10f);
            rscale[tid] = __expf((lun - nowt) * inv30);
            ridx[tid]   = e;
        }
        __syncthreads();

        // ---- stage 2: build feat tile in LDS (bf16) ----
        {
            const int r = tid >> 3;         // row in tile
            const int s = tid & 7;          // col phase
            const int g = row0 + r;
            const float d  = rdecay[r];
            const float ci = rcinv[r];
            const int   e  = ridx[r];
            const float* mrow = memory + (size_t)g*129;
            if (e >= 0) {
                const float* grow = umsg + (size_t)e*129;
                #pragma unroll
                for (int j = 0; j < 16; ++j) {
                    const int c = s + j*8;  // 8 consecutive lanes -> 8 consecutive floats
                    const float ms = fmaf(mrow[c], d, grow[c]);
                    feat[r][c]       = f2b(ms * ci);
                    feat[r][128 + c] = f2b(ms);
                }
            } else {
                #pragma unroll
                for (int j = 0; j < 16; ++j) {
                    const int c = s + j*8;
                    const float ms = mrow[c];
                    feat[r][c]       = f2b(ms * ci);
                    feat[r][128 + c] = f2b(ms);
                }
            }
        }
        __syncthreads();

        // ---- GEMM1: h1 = leaky(feat @ W1 + b1), this wave's 16-col slice ----
        #pragma unroll
        for (int mt = 0; mt < 4; ++mt) {
            f32x4 acc = {0.f, 0.f, 0.f, 0.f};
            const int mrow = mt*16 + l16;   // A: m = lane&15
            #pragma unroll
            for (int k = 0; k < 8; ++k) {
                u16x8 a = *(const u16x8*)&feat[mrow][k*32 + quad*8];  // k = quad*8+j
                acc = __builtin_amdgcn_mfma_f32_16x16x32_bf16(
                        __builtin_bit_cast(bf16x8, a),
                        __builtin_bit_cast(bf16x8, w1f[k]), acc, 0, 0, 0);
            }
            #pragma unroll
            for (int r = 0; r < 4; ++r) {   // C: col = lane&15, row = quad*4 + r
                float v = acc[r] + b1v;
                v = (v >= 0.f) ? v : 0.01f * v;
                h1s[mt*16 + quad*4 + r][wn + l16] = f2b(v);
            }
        }
        __syncthreads();

        // ---- GEMM2 + fused epilogue ----
        #pragma unroll
        for (int mt = 0; mt < 4; ++mt) {
            f32x4 acc = {0.f, 0.f, 0.f, 0.f};
            const int mrow = mt*16 + l16;
            #pragma unroll
            for (int k = 0; k < 4; ++k) {
                u16x8 a = *(const u16x8*)&h1s[mrow][k*32 + quad*8];
                acc = __builtin_amdgcn_mfma_f32_16x16x32_bf16(
                        __builtin_bit_cast(bf16x8, a),
                        __builtin_bit_cast(bf16x8, w2f[k]), acc, 0, 0, 0);
            }
            #pragma unroll
            for (int r = 0; r < 4; ++r) {
                const int row = mt*16 + quad*4 + r;
                const int g = row0 + row;
                float v = acc[r] + b2v;
                v = (v >= 0.f) ? v : 0.01f * v;
                v *= rscale[row];                       // * exp((lu'-now)/OUTPUT)
                const float sv = semb[(size_t)g*128 + wn + l16];
                out[(size_t)g*128 + wn + l16] = el * sv + (1.0f - el) * v;
            }
        }
        __syncthreads();   // protect feat/h1s/r* before next tile
    }
}

extern "C" void kernel_launch(void* const* d_in, const int* in_sizes, int n_in,
                              void* d_out, int out_size, void* d_ws, size_t ws_size,
                              hipStream_t stream) {
    const float* memory      = (const float*)d_in[0];
    const float* last_update = (const float*)d_in[1];
    const float* umsg        = (const float*)d_in[2];
    const float* uts         = (const float*)d_in[3];
    const float* semb        = (const float*)d_in[4];
    const float* W1          = (const float*)d_in[5];
    const float* b1          = (const float*)d_in[6];
    const float* W2          = (const float*)d_in[7];
    const float* b2          = (const float*)d_in[8];
    const float* e_lamb      = (const float*)d_in[9];
    const float* nowt        = (const float*)d_in[10];
    const int*   src         = (const int*)d_in[11];

    int* inv     = (int*)d_ws;            // N ints
    int* counter = inv + N_ROWS;          // 1 int (work-steal)
    float* out   = (float*)d_out;         // fp32 — reference output dtype

    fill_inv<<<(N_ROWS + 255) / 256, 256, 0, stream>>>(inv, counter);
    scatter_inv<<<(E_UPD + 255) / 256, 256, 0, stream>>>(src, inv);
    ctdg_main<<<MAIN_GRID, 512, 0, stream>>>(memory, last_update, umsg, uts, semb,
                                             W1, b1, W2, b2, e_lamb, nowt,
                                             inv, counter, out);
}